// Round 14
// baseline (138.062 us; speedup 1.0000x reference)
//
#include <hip/hip_runtime.h>
#include <math.h>

#define T_ 1024
#define BS_ 8
#define D_ 512
#define NROWS_ (BS_*2*T_)   // 16384
#define ALPHA_ 0.1f

typedef _Float16 f16;
typedef _Float16 f16x8 __attribute__((ext_vector_type(8)));
typedef _Float16 f16x4 __attribute__((ext_vector_type(4)));
typedef _Float16 f16x2 __attribute__((ext_vector_type(2)));
typedef float f32x4 __attribute__((ext_vector_type(4)));

#define MFMA16(A,B,C) __builtin_amdgcn_mfma_f32_16x16x32_f16((A),(B),(C),0,0,0)

__device__ __forceinline__ void gl16(const void* g, void* l) {
    __builtin_amdgcn_global_load_lds(
        (const __attribute__((address_space(1))) unsigned int*)g,
        (__attribute__((address_space(3))) unsigned int*)l, 16, 0, 0);
}

#if __has_builtin(__builtin_amdgcn_fdot2)
__device__ __forceinline__ float fdot2p(f16x2 a, f16x2 b, float c) {
    return __builtin_amdgcn_fdot2(a, b, c, false);
}
#else
__device__ __forceinline__ float fdot2p(f16x2 a, f16x2 b, float c) {
    return fmaf((float)a[1], (float)b[1], fmaf((float)a[0], (float)b[0], c));
}
#endif

__device__ __forceinline__ float fdot8(const f16x8 a, const f16x8 b, float s) {
    #pragma unroll
    for (int q = 0; q < 4; ++q) {
        f16x2 aa, bb;
        aa[0] = a[2*q]; aa[1] = a[2*q+1];
        bb[0] = b[2*q]; bb[1] = b[2*q+1];
        s = fdot2p(aa, bb, s);
    }
    return s;
}

// float -> order-preserving unsigned
__device__ __forceinline__ unsigned sortable(float f) {
    unsigned u = __float_as_uint(f);
    return u ^ ((u & 0x80000000u) ? 0xFFFFFFFFu : 0x80000000u);
}
__device__ __forceinline__ unsigned pack_key(float s, int col) {
    return (sortable(s) & 0xFFFFFC00u) | (unsigned)(1023 - col);
}

#define INSK4(K, X) { \
    bool g3 = (X) > K[3], g2 = (X) > K[2], g1 = (X) > K[1], g0 = (X) > K[0]; \
    K[3] = g2 ? K[2] : (g3 ? (X) : K[3]); \
    K[2] = g1 ? K[1] : (g2 ? (X) : K[2]); \
    K[1] = g0 ? K[0] : (g1 ? (X) : K[1]); \
    K[0] = g0 ? (X) : K[0]; }

#define INSK8(K, X) { \
    bool h7=(X)>K[7],h6=(X)>K[6],h5=(X)>K[5],h4=(X)>K[4]; \
    bool h3=(X)>K[3],h2=(X)>K[2],h1=(X)>K[1],h0=(X)>K[0]; \
    K[7]=h6?K[6]:(h7?(X):K[7]); K[6]=h5?K[5]:(h6?(X):K[6]); \
    K[5]=h4?K[4]:(h5?(X):K[5]); K[4]=h3?K[3]:(h4?(X):K[4]); \
    K[3]=h2?K[2]:(h3?(X):K[3]); K[2]=h1?K[1]:(h2?(X):K[2]); \
    K[1]=h0?K[0]:(h1?(X):K[1]); K[0]=h0?(X):K[0]; }

#define CEU(a,b) { unsigned mx_ = (a) > (b) ? (a) : (b); \
    unsigned mn_ = (a) > (b) ? (b) : (a); (a) = mx_; (b) = mn_; }

#define MERGE8(K, MSK) { \
    unsigned b0=__shfl_xor(K[0],MSK), b1=__shfl_xor(K[1],MSK), \
             b2=__shfl_xor(K[2],MSK), b3=__shfl_xor(K[3],MSK), \
             b4=__shfl_xor(K[4],MSK), b5=__shfl_xor(K[5],MSK), \
             b6=__shfl_xor(K[6],MSK), b7=__shfl_xor(K[7],MSK); \
    K[0]=K[0]>b7?K[0]:b7; K[1]=K[1]>b6?K[1]:b6; \
    K[2]=K[2]>b5?K[2]:b5; K[3]=K[3]>b4?K[3]:b4; \
    K[4]=K[4]>b3?K[4]:b3; K[5]=K[5]>b2?K[5]:b2; \
    K[6]=K[6]>b1?K[6]:b1; K[7]=K[7]>b0?K[7]:b0; \
    CEU(K[0],K[4]); CEU(K[1],K[5]); CEU(K[2],K[6]); CEU(K[3],K[7]); \
    CEU(K[0],K[2]); CEU(K[1],K[3]); CEU(K[4],K[6]); CEU(K[5],K[7]); \
    CEU(K[0],K[1]); CEU(K[2],K[3]); CEU(K[4],K[5]); CEU(K[6],K[7]); }

#define BETTER(x,xi,v,vi) ((x) > (v) || ((x) == (v) && (xi) < (vi)))
#define INS4T(TV,TI,X,ID) { \
    bool g3 = BETTER(X,ID,TV[3],TI[3]), g2 = BETTER(X,ID,TV[2],TI[2]); \
    bool g1 = BETTER(X,ID,TV[1],TI[1]), g0 = BETTER(X,ID,TV[0],TI[0]); \
    TV[3] = g2 ? TV[2] : (g3 ? (X) : TV[3]); TI[3] = g2 ? TI[2] : (g3 ? (ID) : TI[3]); \
    TV[2] = g1 ? TV[1] : (g2 ? (X) : TV[2]); TI[2] = g1 ? TI[1] : (g2 ? (ID) : TI[2]); \
    TV[1] = g0 ? TV[0] : (g1 ? (X) : TV[1]); TI[1] = g0 ? TI[0] : (g1 ? (ID) : TI[1]); \
    TV[0] = g0 ? (X) : TV[0]; TI[0] = g0 ? (ID) : TI[0]; }

// counted-vmcnt pipeline sync (T4)
#define PIPE_WAIT3() { asm volatile("s_waitcnt vmcnt(3)" ::: "memory"); \
    __builtin_amdgcn_s_barrier(); __builtin_amdgcn_sched_barrier(0); }
#define PIPE_WAIT0() { asm volatile("s_waitcnt vmcnt(0)" ::: "memory"); \
    __builtin_amdgcn_s_barrier(); __builtin_amdgcn_sched_barrier(0); }

// ---------- Kernel 0: W (FIN x FOUT) -> WT[n][k] f16 hi/lo ----------
__global__ __launch_bounds__(256) void k_splitW(
    const float* __restrict__ W, f16* __restrict__ WTh, f16* __restrict__ WTl)
{
    __shared__ float tile[64][65];
    const int tid = threadIdx.x;
    const int tk = (blockIdx.x >> 3) << 6, tn = (blockIdx.x & 7) << 6;
    const int r0 = tid >> 4, c4 = (tid & 15) << 2;

    #pragma unroll
    for (int rr = 0; rr < 4; ++rr) {
        int k = r0 + (rr << 4);
        float4 v = *(const float4*)(W + (size_t)(tk + k) * D_ + tn + c4);
        tile[k][c4+0] = v.x; tile[k][c4+1] = v.y;
        tile[k][c4+2] = v.z; tile[k][c4+3] = v.w;
    }
    __syncthreads();
    #pragma unroll
    for (int rr = 0; rr < 4; ++rr) {
        int n = r0 + (rr << 4);
        f16x4 h, l;
        #pragma unroll
        for (int i = 0; i < 4; ++i) {
            float x = tile[c4 + i][n];
            f16 hh = (f16)x; h[i] = hh; l[i] = (f16)(x - (float)hh);
        }
        *(f16x4*)(WTh + (size_t)(tn + n) * D_ + tk + c4) = h;
        *(f16x4*)(WTl + (size_t)(tn + n) * D_ + tk + c4) = l;
    }
}

// ---------- Kernel A: Wh = h @ W — 24KB stages, 3-buf counted vmcnt, 2 blocks/CU ----------
// grid 256 (XCD-swizzled), 512 threads (8 waves: wr2 x wc4); block = 64 rows x 512 cols
// 64 stages tau: kc = tau>>2 (K=32), cq = tau&3 (128 cols). stage = {Bh 8K, Bl 8K, A-f32 8K}
// = uniform 3 gl16/thread. LDS = 3 x 24576 = 73728 -> 2 blocks/CU.
__global__ __launch_bounds__(512, 4) void k_gemm_wh(
    const float* __restrict__ xa, const float* __restrict__ xv,
    const f16* __restrict__ WTh, const f16* __restrict__ WTl,
    const float* __restrict__ a,
    f16* __restrict__ Whh, f16* __restrict__ Whl,
    float* __restrict__ Wh1, float* __restrict__ Wh2, float* __restrict__ sq)
{
    __shared__ __align__(16) unsigned char smem[73728];

    const int tid  = threadIdx.x;
    const int w    = tid >> 6;
    const int wr   = w >> 2, wc = w & 3;
    const int lane = tid & 63;
    const int l15  = lane & 15;
    const int g    = lane >> 4;
    const int bid  = blockIdx.x;
    const int swz  = ((bid & 7) << 5) + (bid >> 3);   // bijective, 256 % 8 == 0
    const int rowbase = swz << 6;

    const int qp = rowbase >> 10;
    const float* xsrc = ((qp & 1) ? xv : xa)
                      + (size_t)((qp >> 1) * 1024 + (rowbase & 1023)) * D_;
    const char* xsrcB = (const char*)xsrc;
    const char* WThB = (const char*)WTh;
    const char* WTlB = (const char*)WTl;

    // B staging: slot tid -> row rB = tid>>2 (0..127), chunk cB = tid&3 of the 64B K-window
    const int rB = tid >> 2, cB = tid & 3;
    const int jB = cB ^ ((rB >> 1) & 3);
    // A staging: slot tid -> row rA = tid>>3 (0..63), chunk16 cA = tid&7 of the 128B K-window
    const int rA = tid >> 3, cA = tid & 7;
    const int jcA = (((cA >> 1) ^ ((rA >> 1) & 3)) << 1) | (cA & 1);
    const size_t gaA_base = (size_t)rA * 2048 + (jcA << 4);   // + kc*128

    // fragment read offsets
    const int swzB = (g ^ ((l15 >> 1) & 3)) << 4;
    const int bo0 = (((wc << 5) + l15) << 6) + swzB;          // c=0 row
    const int bo1 = bo0 + 1024;                               // c=1 (+16 rows)
    const int arow = (wr << 5) + l15;
    const int ar0 = 16384 + (arow << 7) + ((g ^ ((l15 >> 1) & 3)) << 5);

    #define STAGE(tau_, bb_) { \
        const int kc_ = (tau_) >> 2, cq_ = (tau_) & 3; \
        const size_t gB_ = ((size_t)((cq_ << 7) + rB) << 10) + ((size_t)kc_ << 6) + (jB << 4); \
        gl16(WThB + gB_, smem + (bb_) + (tid << 4)); \
        gl16(WTlB + gB_, smem + (bb_) + 8192 + (tid << 4)); \
        gl16(xsrcB + gaA_base + ((size_t)kc_ << 7), smem + (bb_) + 16384 + (tid << 4)); }

    #define CONVA(H, L, p0, p1) { \
        float xs_[8] = {p0[0],p0[1],p0[2],p0[3],p1[0],p1[1],p1[2],p1[3]}; \
        _Pragma("unroll") \
        for (int e_ = 0; e_ < 8; ++e_) { \
            f16 hh_ = (f16)xs_[e_]; H[e_] = hh_; L[e_] = (f16)(xs_[e_] - (float)hh_); } }

    #define COMPUTE(ACC, BB) { \
        f32x4 u0 = *(const f32x4*)(smem + (BB) + ar0); \
        f32x4 u1 = *(const f32x4*)(smem + (BB) + ar0 + 16); \
        f32x4 v0 = *(const f32x4*)(smem + (BB) + ar0 + 2048); \
        f32x4 v1 = *(const f32x4*)(smem + (BB) + ar0 + 2048 + 16); \
        f16x8 AH0, AL0, AH1, AL1; \
        CONVA(AH0, AL0, u0, u1); \
        CONVA(AH1, AL1, v0, v1); \
        f16x8 bh0 = *(const f16x8*)(smem + (BB) + bo0); \
        f16x8 bh1 = *(const f16x8*)(smem + (BB) + bo1); \
        f16x8 bl0 = *(const f16x8*)(smem + (BB) + 8192 + bo0); \
        f16x8 bl1 = *(const f16x8*)(smem + (BB) + 8192 + bo1); \
        ACC[0][0] = MFMA16(AH0, bh0, ACC[0][0]); \
        ACC[0][1] = MFMA16(AH0, bh1, ACC[0][1]); \
        ACC[1][0] = MFMA16(AH1, bh0, ACC[1][0]); \
        ACC[1][1] = MFMA16(AH1, bh1, ACC[1][1]); \
        ACC[0][0] = MFMA16(AL0, bh0, ACC[0][0]); \
        ACC[0][1] = MFMA16(AL0, bh1, ACC[0][1]); \
        ACC[1][0] = MFMA16(AL1, bh0, ACC[1][0]); \
        ACC[1][1] = MFMA16(AL1, bh1, ACC[1][1]); \
        ACC[0][0] = MFMA16(AH0, bl0, ACC[0][0]); \
        ACC[0][1] = MFMA16(AH0, bl1, ACC[0][1]); \
        ACC[1][0] = MFMA16(AH1, bl0, ACC[1][0]); \
        ACC[1][1] = MFMA16(AH1, bl1, ACC[1][1]); }

    f32x4 accA[2][2], accB[2][2], accC[2][2], accD[2][2];
    #pragma unroll
    for (int m = 0; m < 2; ++m)
        #pragma unroll
        for (int c = 0; c < 2; ++c) {
            accA[m][c] = (f32x4){0.f,0.f,0.f,0.f};
            accB[m][c] = (f32x4){0.f,0.f,0.f,0.f};
            accC[m][c] = (f32x4){0.f,0.f,0.f,0.f};
            accD[m][c] = (f32x4){0.f,0.f,0.f,0.f};
        }

    STAGE(0, 0);
    STAGE(1, 24576);

    int tau = 2;                 // next stage to issue; buffer = tau%3
    int sb  = 49152;
    int cb  = 0;                 // compute buffer = t%3
    #define ADV(p_) { p_ += 24576; if (p_ == 73728) p_ = 0; }
    #define STEPX(ACC) { \
        PIPE_WAIT3(); \
        STAGE(tau, sb); ++tau; ADV(sb); \
        COMPUTE(ACC, cb); ADV(cb); }

    for (int kk = 0; kk < 15; ++kk) {
        STEPX(accA); STEPX(accB); STEPX(accC); STEPX(accD);
    }
    // peeled tail: t = 60..63 (stages 62,63 issued at t=60,61)
    STEPX(accA);
    STEPX(accB);
    PIPE_WAIT3();
    COMPUTE(accC, cb); ADV(cb);
    PIPE_WAIT0();
    COMPUTE(accD, cb);
    #undef STEPX
    #undef ADV
    #undef STAGE
    #undef COMPUTE
    #undef CONVA

    __syncthreads();   // all compute done; LDS free for bounce

    // ---- epilogue: stats + coalesced hi/lo writes via LDS bounce ----
    float st1[8], st2[8], stq[8];
    #pragma unroll
    for (int s = 0; s < 8; ++s) { st1[s] = 0.f; st2[s] = 0.f; stq[s] = 0.f; }

    f16* dump = (f16*)smem;   // 64 rows x 512 cols f16 = 64KB

    #define DUMP_HI(ACC, CQ) { \
        _Pragma("unroll") \
        for (int c = 0; c < 2; ++c) { \
            const int col = ((CQ) << 7) + (wc << 5) + (c << 4) + l15; \
            const float a1 = a[col]; \
            const float a2 = a[512 + col]; \
            _Pragma("unroll") \
            for (int m = 0; m < 2; ++m) \
            _Pragma("unroll") \
            for (int j = 0; j < 4; ++j) { \
                const float v = ACC[m][c][j]; \
                const int slot = (m << 2) + j; \
                st1[slot] = fmaf(v, a1, st1[slot]); \
                st2[slot] = fmaf(v, a2, st2[slot]); \
                stq[slot] = fmaf(v, v,  stq[slot]); \
                const int row = (wr << 5) + (m << 4) + (g << 2) + j; \
                dump[(row << 9) + col] = (f16)v; \
            } } }

    #define DUMP_LO(ACC, CQ) { \
        _Pragma("unroll") \
        for (int c = 0; c < 2; ++c) { \
            const int col = ((CQ) << 7) + (wc << 5) + (c << 4) + l15; \
            _Pragma("unroll") \
            for (int m = 0; m < 2; ++m) \
            _Pragma("unroll") \
            for (int j = 0; j < 4; ++j) { \
                const float v = ACC[m][c][j]; \
                const f16 h = (f16)v; \
                const int row = (wr << 5) + (m << 4) + (g << 2) + j; \
                dump[(row << 9) + col] = (f16)(v - (float)h); \
            } } }

    DUMP_HI(accA, 0); DUMP_HI(accB, 1); DUMP_HI(accC, 2); DUMP_HI(accD, 3);
    __syncthreads();
    {   // coalesced store of hi: thread covers 64 consecutive f16
        const f16* srcp = dump + (tid << 6);
        f16* dstp = Whh + ((size_t)rowbase << 9) + (tid << 6);
        #pragma unroll
        for (int k = 0; k < 8; ++k)
            *(f16x8*)(dstp + (k << 3)) = *(const f16x8*)(srcp + (k << 3));
    }
    __syncthreads();
    DUMP_LO(accA, 0); DUMP_LO(accB, 1); DUMP_LO(accC, 2); DUMP_LO(accD, 3);
    __syncthreads();
    {
        const f16* srcp = dump + (tid << 6);
        f16* dstp = Whl + ((size_t)rowbase << 9) + (tid << 6);
        #pragma unroll
        for (int k = 0; k < 8; ++k)
            *(f16x8*)(dstp + (k << 3)) = *(const f16x8*)(srcp + (k << 3));
    }
    __syncthreads();
    #undef DUMP_HI
    #undef DUMP_LO

    #pragma unroll
    for (int mask = 1; mask < 16; mask <<= 1)
        #pragma unroll
        for (int s = 0; s < 8; ++s) {
            st1[s] += __shfl_xor(st1[s], mask);
            st2[s] += __shfl_xor(st2[s], mask);
            stq[s] += __shfl_xor(stq[s], mask);
        }
    if (l15 == 0) {
        #pragma unroll
        for (int s = 0; s < 8; ++s) {
            const int rl = (wr << 5) + ((s >> 2) << 4) + (g << 2) + (s & 3);
            float* sp = (float*)(smem + 65536) + ((rl << 2) + wc) * 3;
            sp[0] = st1[s]; sp[1] = st2[s]; sp[2] = stq[s];
        }
    }
    __syncthreads();
    if (tid < 64) {
        float s1 = 0.f, s2 = 0.f, s3 = 0.f;
        #pragma unroll
        for (int wv = 0; wv < 4; ++wv) {
            const float* sp = (const float*)(smem + 65536) + ((tid << 2) + wv) * 3;
            s1 += sp[0]; s2 += sp[1]; s3 += sp[2];
        }
        Wh1[rowbase + tid] = s1; Wh2[rowbase + tid] = s2; sq[rowbase + tid] = s3;
    }
}

// ---------- Kernel C: single-pass f16 gram, 2-phase LDS dbuf, fused top-8 ----------
// (verbatim round-9 version — proven)
__global__ __launch_bounds__(512, 1) void k_gram_topk8(
    const f16* __restrict__ Whh, const float* __restrict__ sq,
    int* __restrict__ topk8)
{
    __shared__ __align__(16) unsigned char smem[81920];

    const int bid = blockIdx.x;
    const int swz = ((bid & 7) << 5) + (bid >> 3);
    const int p   = swz >> 4;
    const int rt  = swz & 15;
    const int rowbase  = (p << 10) + (rt << 6);
    const int colPanel = p << 10;

    const int tid  = threadIdx.x;
    const int w    = tid >> 6;
    const int wr   = w >> 2, wc = w & 3;
    const int lane = tid & 63;
    const int l15  = lane & 15;
    const int g    = lane >> 4;
    const int r8   = lane >> 3;
    const int k7   = lane & 7;
    const int sw2  = ((k7 ^ r8) << 4);
    const int q0x  = ((g ^ (lane & 7)) << 4);

    const int rowA = tid >> 3;
    const int k7A  = tid & 7;
    const int aswz = ((k7A ^ (rowA & 7)) << 4);

    const char* WB = (const char*)Whh;

    const int aoff0 = 32768 + (((wr << 5) +  0 + l15) << 7) + q0x;
    const int aoff1 = 32768 + (((wr << 5) + 16 + l15) << 7) + q0x;
    const int boff0 = (((wc << 6) +  0 + l15) << 7) + q0x;
    const int boff1 = (((wc << 6) + 16 + l15) << 7) + q0x;
    const int boff2 = (((wc << 6) + 32 + l15) << 7) + q0x;
    const int boff3 = (((wc << 6) + 48 + l15) << 7) + q0x;

    f32x4 acc[2][4];
    #pragma unroll
    for (int m = 0; m < 2; ++m)
        #pragma unroll
        for (int c = 0; c < 4; ++c) acc[m][c] = (f32x4){0.f,0.f,0.f,0.f};

    unsigned k4[8][4];
    #pragma unroll
    for (int s = 0; s < 8; ++s)
        #pragma unroll
        for (int q = 0; q < 4; ++q) k4[s][q] = 0u;

    #define STAGE_G(t) { \
        const int ct_ = (t) >> 3, kc_ = (t) & 7; \
        const int bufb_ = ((t) & 1) * 40960; \
        size_t gB_ = ((size_t)(colPanel + (ct_ << 8) + (w << 5) + r8) << 10) + (kc_ << 7) + sw2; \
        int ldsB_ = bufb_ + (w << 12) + (lane << 4); \
        _Pragma("unroll") \
        for (int j_ = 0; j_ < 4; ++j_) { \
            gl16(WB + gB_, smem + ldsB_); \
            gB_ += (size_t)8 << 10; ldsB_ += 1024; \
        } \
        size_t gA_ = ((size_t)(rowbase + rowA) << 10) + (kc_ << 7) + aswz; \
        gl16(WB + gA_, smem + bufb_ + 32768 + (tid << 4)); \
    }

    STAGE_G(0);

    for (int t = 0; t < 32; ++t) {
        __syncthreads();
        if (t < 31) STAGE_G(t + 1);
        const int bufb = (t & 1) * 40960;

        #pragma unroll
        for (int s = 0; s < 2; ++s) {
            const int sx = s << 6;
            f16x8 a0 = *(const f16x8*)(smem + bufb + (aoff0 ^ sx));
            f16x8 a1 = *(const f16x8*)(smem + bufb + (aoff1 ^ sx));
            f16x8 b0 = *(const f16x8*)(smem + bufb + (boff0 ^ sx));
            f16x8 b1 = *(const f16x8*)(smem + bufb + (boff1 ^ sx));
            f16x8 b2 = *(const f16x8*)(smem + bufb + (boff2 ^ sx));
            f16x8 b3 = *(const f16x8*)(smem + bufb + (boff3 ^ sx));
            acc[0][0] = MFMA16(a0, b0, acc[0][0]);
            acc[0][1] = MFMA16(a0, b1, acc[0][1]);
            acc[0][2] = MFMA16(a0, b2, acc[0][2]);
            acc[0][3] = MFMA16(a0, b3, acc[0][3]);
            acc[1][0] = MFMA16(a1, b0, acc[1][0]);
            acc[1][1] = MFMA16(a1, b1, acc[1][1]);
            acc[1][2] = MFMA16(a1, b2, acc[1][2]);
            acc[1][3] = MFMA16(a1, b3, acc[1][3]);
        }

        if ((t & 7) == 7) {
            const int ct = t >> 3;
            #pragma unroll
            for (int c = 0; c < 4; ++c) {
                const int cl = (ct << 8) + (wc << 6) + (c << 4) + l15;
                const float sqc = sq[colPanel + cl];
                #pragma unroll
                for (int m = 0; m < 2; ++m)
                    #pragma unroll
                    for (int j = 0; j < 4; ++j) {
                        float sc = fmaf(2.f, acc[m][c][j], -sqc);
                        unsigned key = pack_key(sc, cl);
                        INSK4(k4[(m << 2) + j], key);
                    }
                acc[0][c] = (f32x4){0.f,0.f,0.f,0.f};
                acc[1][c] = (f32x4){0.f,0.f,0.f,0.f};
            }
        }
    }

    unsigned k8[8][8];
    #pragma unroll
    for (int s = 0; s < 8; ++s) {
        #pragma unroll
        for (int q = 0; q < 4; ++q) { k8[s][q] = k4[s][q]; k8[s][4 + q] = 0u; }
    }
    #pragma unroll
    for (int msk = 1; msk < 16; msk <<= 1) {
        #pragma unroll
        for (int s = 0; s < 8; ++s) { MERGE8(k8[s], msk); }
    }

    if (l15 == 0) {
        #pragma unroll
        for (int s = 0; s < 8; ++s) {
            const int row_local = ((s >> 2) << 4) + (g << 2) + (s & 3);
            const int off = ((((wr << 5) + row_local) << 2) + wc) << 5;
            *(uint4*)(smem + off)      = make_uint4(k8[s][0], k8[s][1], k8[s][2], k8[s][3]);
            *(uint4*)(smem + off + 16) = make_uint4(k8[s][4], k8[s][5], k8[s][6], k8[s][7]);
        }
    }
    __syncthreads();
    if (tid < 64) {
        const unsigned* bp = (const unsigned*)smem + (tid << 5);
        unsigned kk[8];
        #pragma unroll
        for (int s = 0; s < 8; ++s) kk[s] = bp[s];
        #pragma unroll
        for (int wv = 1; wv < 4; ++wv)
            #pragma unroll
            for (int s = 0; s < 8; ++s) { unsigned x = bp[(wv << 3) + s]; INSK8(kk, x); }
        #pragma unroll
        for (int s = 0; s < 8; ++s)
            topk8[(((size_t)(rowbase + tid)) << 3) + s] = 1023 - (int)(kk[s] & 1023u);
    }
    #undef STAGE_G
}

// ---------- Kernel D: exact rescore (fdot2) + softmax + hi-only aggregate + elu ----------
// (unchanged from round 13)
__global__ __launch_bounds__(256) void k_rescore_agg(
    const f16* __restrict__ Whh, const f16* __restrict__ Whl,
    const float* __restrict__ Wh1, const float* __restrict__ Wh2,
    const float* __restrict__ sq, const int* __restrict__ topk8,
    float* __restrict__ out)
{
    const int bid = blockIdx.x;
    const int swz = ((bid & 7) << 9) + (bid >> 3);
    const int tid  = threadIdx.x;
    const int lane = tid & 63;
    const int r    = (swz << 2) + (tid >> 6);
    const int p    = r >> 10;
    const int i    = r & 1023;
    const int rb   = p << 10;

    const size_t ro = (size_t)r * D_ + (lane << 3);
    f16x8 ah = *(const f16x8*)(Whh + ro);
    f16x8 al = *(const f16x8*)(Whl + ro);

    int cid[8];
    {
        int4 t0 = *(const int4*)(topk8 + ((size_t)r << 3));
        int4 t1 = *(const int4*)(topk8 + ((size_t)r << 3) + 4);
        cid[0]=t0.x; cid[1]=t0.y; cid[2]=t0.z; cid[3]=t0.w;
        cid[4]=t1.x; cid[5]=t1.y; cid[6]=t1.z; cid[7]=t1.w;
    }

    float dp[8];
    #pragma unroll
    for (int c = 0; c < 8; ++c) {
        const size_t co = (size_t)(rb + cid[c]) * D_ + (lane << 3);
        f16x8 bh = *(const f16x8*)(Whh + co);
        f16x8 bl = *(const f16x8*)(Whl + co);
        float s = 0.f;
        s = fdot8(ah, bh, s);
        s = fdot8(ah, bl, s);
        s = fdot8(al, bh, s);
        dp[c] = s;
    }
    #pragma unroll
    for (int off = 32; off > 0; off >>= 1)
        #pragma unroll
        for (int c = 0; c < 8; ++c) dp[c] += __shfl_xor(dp[c], off);

    float tv[4] = {-3.4e38f,-3.4e38f,-3.4e38f,-3.4e38f};
    int   ti[4] = {0x7FFFFFFF,0x7FFFFFFF,0x7FFFFFFF,0x7FFFFFFF};
    #pragma unroll
    for (int c = 0; c < 8; ++c) {
        float sc = fmaf(2.f, dp[c], -sq[rb + cid[c]]);
        INS4T(tv, ti, sc, cid[c]);
    }

    const int  tM = i - 1, tC = i, tP = i + 1;
    const bool vM = (i > 0), vP = (i < T_ - 1);
    const int s0 = ti[0], s1 = ti[1], s2 = ti[2], s3 = ti[3];

    bool u0 = !((vM && s0 == tM) || (s0 == tC) || (vP && s0 == tP));
    bool u1 = !((vM && s1 == tM) || (s1 == tC) || (vP && s1 == tP));
    bool u2 = !((vM && s2 == tM) || (s2 == tC) || (vP && s2 == tP));
    bool u3 = !((vM && s3 == tM) || (s3 == tC) || (vP && s3 == tP));

    int  ci[7] = { vM ? tM : 0, tC, vP ? tP : 0, s0, s1, s2, s3 };
    bool cv[7] = { vM, true, vP, u0, u1, u2, u3 };

    f16x8 vhq[7];
    #pragma unroll
    for (int q = 0; q < 7; ++q)
        vhq[q] = *(const f16x8*)(Whh + (size_t)(rb + ci[q]) * D_ + (lane << 3));

    const float e1 = Wh1[r];
    float ev[7];
    float m = -3.4e38f;
    #pragma unroll
    for (int q = 0; q < 7; ++q) {
        float e = e1 + Wh2[rb + ci[q]];
        e = (e > 0.f) ? e : ALPHA_ * e;
        e = cv[q] ? e : -3.4e38f;
        ev[q] = e;
        m = fmaxf(m, e);
    }
    float wsum = 0.f;
    #pragma unroll
    for (int q = 0; q < 7; ++q) {
        float wq = cv[q] ? expf(ev[q] - m) : 0.f;
        ev[q] = wq;
        wsum += wq;
    }
    #pragma unroll
    for (int q = 0; q < 7; ++q) ev[q] /= wsum;

    float A[8] = {0.f,0.f,0.f,0.f,0.f,0.f,0.f,0.f};
    #pragma unroll
    for (int q = 0; q < 7; ++q) {
        const float wq = ev[q];
        #pragma unroll
        for (int e = 0; e < 8; ++e) A[e] = fmaf(wq, (float)vhq[q][e], A[e]);
    }
    #pragma unroll
    for (int e = 0; e < 8; ++e)
        A[e] = (A[e] > 0.f) ? A[e] : expm1f(A[e]);

    const int blk = p & 1, b = p >> 1;
    float* dst = out + (size_t)blk * ((size_t)BS_ * T_ * D_)
               + ((size_t)((b << 10) + i)) * D_ + (lane << 3);
    *(float4*)(dst)     = make_float4(A[0], A[1], A[2], A[3]);
    *(float4*)(dst + 4) = make_float4(A[4], A[5], A[6], A[7]);
}

extern "C" void kernel_launch(void* const* d_in, const int* in_sizes, int n_in,
                              void* d_out, int out_size, void* d_ws, size_t ws_size,
                              hipStream_t stream)
{
    const float* xa = (const float*)d_in[0];
    const float* xv = (const float*)d_in[1];
    const float* W  = (const float*)d_in[2];
    const float* a  = (const float*)d_in[3];
    float* out = (float*)d_out;

    f16* Whh    = (f16*)d_ws;                          // 16.8 MB
    f16* Whl    = Whh + (size_t)NROWS_ * D_;           // 16.8 MB
    f16* WTh    = Whl + (size_t)NROWS_ * D_;           // 0.5 MB
    f16* WTl    = WTh + (size_t)D_ * D_;               // 0.5 MB
    float* Wh1  = (float*)(WTl + (size_t)D_ * D_);
    float* Wh2  = Wh1 + NROWS_;
    float* sq   = Wh2 + NROWS_;
    int* topk8  = (int*)(sq + NROWS_);                 // 0.5 MB

    k_splitW     <<<dim3(64),   dim3(256), 0, stream>>>(W, WTh, WTl);
    k_gemm_wh    <<<dim3(256),  dim3(512), 0, stream>>>(xa, xv, WTh, WTl, a, Whh, Whl, Wh1, Wh2, sq);
    k_gram_topk8 <<<dim3(256),  dim3(512), 0, stream>>>(Whh, sq, topk8);
    k_rescore_agg<<<dim3(4096), dim3(256), 0, stream>>>(Whh, Whl, Wh1, Wh2, sq, topk8, out);
}

// Round 15
// 121.520 us; speedup vs baseline: 1.1361x; 1.1361x over previous
//
#include <hip/hip_runtime.h>
#include <math.h>

#define T_ 1024
#define BS_ 8
#define D_ 512
#define NROWS_ (BS_*2*T_)   // 16384
#define ALPHA_ 0.1f

typedef _Float16 f16;
typedef _Float16 f16x8 __attribute__((ext_vector_type(8)));
typedef _Float16 f16x4 __attribute__((ext_vector_type(4)));
typedef _Float16 f16x2 __attribute__((ext_vector_type(2)));
typedef float f32x4 __attribute__((ext_vector_type(4)));

#define MFMA16(A,B,C) __builtin_amdgcn_mfma_f32_16x16x32_f16((A),(B),(C),0,0,0)

__device__ __forceinline__ void gl16(const void* g, void* l) {
    __builtin_amdgcn_global_load_lds(
        (const __attribute__((address_space(1))) unsigned int*)g,
        (__attribute__((address_space(3))) unsigned int*)l, 16, 0, 0);
}

#if __has_builtin(__builtin_amdgcn_fdot2)
__device__ __forceinline__ float fdot2p(f16x2 a, f16x2 b, float c) {
    return __builtin_amdgcn_fdot2(a, b, c, false);
}
#else
__device__ __forceinline__ float fdot2p(f16x2 a, f16x2 b, float c) {
    return fmaf((float)a[1], (float)b[1], fmaf((float)a[0], (float)b[0], c));
}
#endif

__device__ __forceinline__ float fdot8(const f16x8 a, const f16x8 b, float s) {
    #pragma unroll
    for (int q = 0; q < 4; ++q) {
        f16x2 aa, bb;
        aa[0] = a[2*q]; aa[1] = a[2*q+1];
        bb[0] = b[2*q]; bb[1] = b[2*q+1];
        s = fdot2p(aa, bb, s);
    }
    return s;
}

// float -> order-preserving unsigned
__device__ __forceinline__ unsigned sortable(float f) {
    unsigned u = __float_as_uint(f);
    return u ^ ((u & 0x80000000u) ? 0xFFFFFFFFu : 0x80000000u);
}
__device__ __forceinline__ unsigned pack_key(float s, int col) {
    return (sortable(s) & 0xFFFFFC00u) | (unsigned)(1023 - col);
}

#define INSK4(K, X) { \
    bool g3 = (X) > K[3], g2 = (X) > K[2], g1 = (X) > K[1], g0 = (X) > K[0]; \
    K[3] = g2 ? K[2] : (g3 ? (X) : K[3]); \
    K[2] = g1 ? K[1] : (g2 ? (X) : K[2]); \
    K[1] = g0 ? K[0] : (g1 ? (X) : K[1]); \
    K[0] = g0 ? (X) : K[0]; }

#define INSK8(K, X) { \
    bool h7=(X)>K[7],h6=(X)>K[6],h5=(X)>K[5],h4=(X)>K[4]; \
    bool h3=(X)>K[3],h2=(X)>K[2],h1=(X)>K[1],h0=(X)>K[0]; \
    K[7]=h6?K[6]:(h7?(X):K[7]); K[6]=h5?K[5]:(h6?(X):K[6]); \
    K[5]=h4?K[4]:(h5?(X):K[5]); K[4]=h3?K[3]:(h4?(X):K[4]); \
    K[3]=h2?K[2]:(h3?(X):K[3]); K[2]=h1?K[1]:(h2?(X):K[2]); \
    K[1]=h0?K[0]:(h1?(X):K[1]); K[0]=h0?(X):K[0]; }

#define CEU(a,b) { unsigned mx_ = (a) > (b) ? (a) : (b); \
    unsigned mn_ = (a) > (b) ? (b) : (a); (a) = mx_; (b) = mn_; }

#define MERGE8(K, MSK) { \
    unsigned b0=__shfl_xor(K[0],MSK), b1=__shfl_xor(K[1],MSK), \
             b2=__shfl_xor(K[2],MSK), b3=__shfl_xor(K[3],MSK), \
             b4=__shfl_xor(K[4],MSK), b5=__shfl_xor(K[5],MSK), \
             b6=__shfl_xor(K[6],MSK), b7=__shfl_xor(K[7],MSK); \
    K[0]=K[0]>b7?K[0]:b7; K[1]=K[1]>b6?K[1]:b6; \
    K[2]=K[2]>b5?K[2]:b5; K[3]=K[3]>b4?K[3]:b4; \
    K[4]=K[4]>b3?K[4]:b3; K[5]=K[5]>b2?K[5]:b2; \
    K[6]=K[6]>b1?K[6]:b1; K[7]=K[7]>b0?K[7]:b0; \
    CEU(K[0],K[4]); CEU(K[1],K[5]); CEU(K[2],K[6]); CEU(K[3],K[7]); \
    CEU(K[0],K[2]); CEU(K[1],K[3]); CEU(K[4],K[6]); CEU(K[5],K[7]); \
    CEU(K[0],K[1]); CEU(K[2],K[3]); CEU(K[4],K[5]); CEU(K[6],K[7]); }

#define BETTER(x,xi,v,vi) ((x) > (v) || ((x) == (v) && (xi) < (vi)))
#define INS4T(TV,TI,X,ID) { \
    bool g3 = BETTER(X,ID,TV[3],TI[3]), g2 = BETTER(X,ID,TV[2],TI[2]); \
    bool g1 = BETTER(X,ID,TV[1],TI[1]), g0 = BETTER(X,ID,TV[0],TI[0]); \
    TV[3] = g2 ? TV[2] : (g3 ? (X) : TV[3]); TI[3] = g2 ? TI[2] : (g3 ? (ID) : TI[3]); \
    TV[2] = g1 ? TV[1] : (g2 ? (X) : TV[2]); TI[2] = g1 ? TI[1] : (g2 ? (ID) : TI[2]); \
    TV[1] = g0 ? TV[0] : (g1 ? (X) : TV[1]); TI[1] = g0 ? TI[0] : (g1 ? (ID) : TI[1]); \
    TV[0] = g0 ? (X) : TV[0]; TI[0] = g0 ? (ID) : TI[0]; }

// counted-vmcnt pipeline sync (T4): wait for oldest stage only, never drain in-loop
#define PIPE_WAIT5() { asm volatile("s_waitcnt vmcnt(5)" ::: "memory"); \
    __builtin_amdgcn_s_barrier(); __builtin_amdgcn_sched_barrier(0); }
#define PIPE_WAIT0() { asm volatile("s_waitcnt vmcnt(0)" ::: "memory"); \
    __builtin_amdgcn_s_barrier(); __builtin_amdgcn_sched_barrier(0); }

// ---------- Kernel 0: W (FIN x FOUT) -> WT[n][k] f16 hi/lo ----------
__global__ __launch_bounds__(256) void k_splitW(
    const float* __restrict__ W, f16* __restrict__ WTh, f16* __restrict__ WTl)
{
    __shared__ float tile[64][65];
    const int tid = threadIdx.x;
    const int tk = (blockIdx.x >> 3) << 6, tn = (blockIdx.x & 7) << 6;
    const int r0 = tid >> 4, c4 = (tid & 15) << 2;

    #pragma unroll
    for (int rr = 0; rr < 4; ++rr) {
        int k = r0 + (rr << 4);
        float4 v = *(const float4*)(W + (size_t)(tk + k) * D_ + tn + c4);
        tile[k][c4+0] = v.x; tile[k][c4+1] = v.y;
        tile[k][c4+2] = v.z; tile[k][c4+3] = v.w;
    }
    __syncthreads();
    #pragma unroll
    for (int rr = 0; rr < 4; ++rr) {
        int n = r0 + (rr << 4);
        f16x4 h, l;
        #pragma unroll
        for (int i = 0; i < 4; ++i) {
            float x = tile[c4 + i][n];
            f16 hh = (f16)x; h[i] = hh; l[i] = (f16)(x - (float)hh);
        }
        *(f16x4*)(WTh + (size_t)(tn + n) * D_ + tk + c4) = h;
        *(f16x4*)(WTl + (size_t)(tn + n) * D_ + tk + c4) = l;
    }
}

// ---------- Kernel A: Wh = h @ W — 3-buffer counted-vmcnt pipeline (r13) ----------
// grid 256 (XCD-swizzled), 512 threads (8 waves: wr2 x wc4); block = 64 rows x 512 cols
// 32 stages tau: (cq = tau&1, kc = tau>>1); stage = {B 256col x K32 hi/lo 32KB, A 64row x K32 f32 8KB}
// = uniform 5 gl16/thread. LDS = 3 x 40960 = 122880.
// NEW vs r13: epilogue LDS-bounce -> fully coalesced 128B/thread Whh/Whl stores.
__global__ __launch_bounds__(512, 2) void k_gemm_wh(
    const float* __restrict__ xa, const float* __restrict__ xv,
    const f16* __restrict__ WTh, const f16* __restrict__ WTl,
    const float* __restrict__ a,
    f16* __restrict__ Whh, f16* __restrict__ Whl,
    float* __restrict__ Wh1, float* __restrict__ Wh2, float* __restrict__ sq)
{
    __shared__ __align__(16) unsigned char smem[122880];

    const int tid  = threadIdx.x;
    const int w    = tid >> 6;
    const int wr   = w >> 2, wc = w & 3;
    const int lane = tid & 63;
    const int l15  = lane & 15;
    const int g    = lane >> 4;
    const int bid  = blockIdx.x;
    const int swz  = ((bid & 7) << 5) + (bid >> 3);   // bijective, 256 % 8 == 0
    const int rowbase = swz << 6;

    const int qp = rowbase >> 10;
    const float* xsrc = ((qp & 1) ? xv : xa)
                      + (size_t)((qp >> 1) * 1024 + (rowbase & 1023)) * D_;
    const char* xsrcB = (const char*)xsrc;
    const char* WThB = (const char*)WTh;
    const char* WTlB = (const char*)WTl;

    // B staging: slots tid, tid+512. slot s -> row r=s>>2 (0..255), chunk c=s&3;
    // global K-chunk16 j = c ^ ((r>>1)&3)  (involution; matches read swizzle)
    const int rB1 = tid >> 2,          cB1 = tid & 3;
    const int jB1 = cB1 ^ ((rB1 >> 1) & 3);
    const int rB2 = (tid + 512) >> 2,  cB2 = tid & 3;
    const int jB2 = cB2 ^ ((rB2 >> 1) & 3);

    // A staging: slot tid -> row tid>>3 (0..63), chunk16 tid&7 of the 128B K-window
    const int rA = tid >> 3, cA = tid & 7;
    const int jcA = (((cA >> 1) ^ ((rA >> 1) & 3)) << 1) | (cA & 1);
    const size_t gaA_base = (size_t)rA * 2048 + (jcA << 4);   // + kc*128

    // fragment read offsets
    const int swzx = (g ^ ((l15 >> 1) & 3)) << 4;
    const int bo0 = (((wc << 6) +  0 + l15) << 6) + swzx;
    const int bo1 = (((wc << 6) + 16 + l15) << 6) + swzx;
    const int bo2 = (((wc << 6) + 32 + l15) << 6) + swzx;
    const int bo3 = (((wc << 6) + 48 + l15) << 6) + swzx;
    const int arow = (wr << 5) + l15;
    const int ar0 = (arow << 7) + ((g ^ ((arow >> 1) & 3)) << 5);   // f32 chunk32 swizzle

    #define STAGE(kc_, cq_, bb_) { \
        const size_t g1_ = ((size_t)(((cq_) << 8) + rB1) << 10) + ((size_t)(kc_) << 6) + (jB1 << 4); \
        const size_t g2_ = ((size_t)(((cq_) << 8) + rB2) << 10) + ((size_t)(kc_) << 6) + (jB2 << 4); \
        gl16(WThB + g1_, smem + (bb_) + (tid << 4)); \
        gl16(WThB + g2_, smem + (bb_) + ((tid + 512) << 4)); \
        gl16(WTlB + g1_, smem + (bb_) + 16384 + (tid << 4)); \
        gl16(WTlB + g2_, smem + (bb_) + 16384 + ((tid + 512) << 4)); \
        gl16(xsrcB + gaA_base + ((size_t)(kc_) << 7), smem + (bb_) + 32768 + (tid << 4)); }

    #define CONVA(H, L, p0, p1) { \
        float xs_[8] = {p0[0],p0[1],p0[2],p0[3],p1[0],p1[1],p1[2],p1[3]}; \
        _Pragma("unroll") \
        for (int e_ = 0; e_ < 8; ++e_) { \
            f16 hh_ = (f16)xs_[e_]; H[e_] = hh_; L[e_] = (f16)(xs_[e_] - (float)hh_); } }

    #define COMPUTE(ACC, BB) { \
        f32x4 u0 = *(const f32x4*)(smem + (BB) + 32768 + ar0); \
        f32x4 u1 = *(const f32x4*)(smem + (BB) + 32768 + ar0 + 16); \
        f32x4 v0 = *(const f32x4*)(smem + (BB) + 32768 + ar0 + 2048); \
        f32x4 v1 = *(const f32x4*)(smem + (BB) + 32768 + ar0 + 2048 + 16); \
        f16x8 AH0, AL0, AH1, AL1; \
        CONVA(AH0, AL0, u0, u1); \
        CONVA(AH1, AL1, v0, v1); \
        f16x8 bh0 = *(const f16x8*)(smem + (BB) + bo0); \
        f16x8 bh1 = *(const f16x8*)(smem + (BB) + bo1); \
        f16x8 bh2 = *(const f16x8*)(smem + (BB) + bo2); \
        f16x8 bh3 = *(const f16x8*)(smem + (BB) + bo3); \
        f16x8 bl0 = *(const f16x8*)(smem + (BB) + 16384 + bo0); \
        f16x8 bl1 = *(const f16x8*)(smem + (BB) + 16384 + bo1); \
        f16x8 bl2 = *(const f16x8*)(smem + (BB) + 16384 + bo2); \
        f16x8 bl3 = *(const f16x8*)(smem + (BB) + 16384 + bo3); \
        ACC[0][0] = MFMA16(AH0, bh0, ACC[0][0]); \
        ACC[0][1] = MFMA16(AH0, bh1, ACC[0][1]); \
        ACC[0][2] = MFMA16(AH0, bh2, ACC[0][2]); \
        ACC[0][3] = MFMA16(AH0, bh3, ACC[0][3]); \
        ACC[1][0] = MFMA16(AH1, bh0, ACC[1][0]); \
        ACC[1][1] = MFMA16(AH1, bh1, ACC[1][1]); \
        ACC[1][2] = MFMA16(AH1, bh2, ACC[1][2]); \
        ACC[1][3] = MFMA16(AH1, bh3, ACC[1][3]); \
        ACC[0][0] = MFMA16(AL0, bh0, ACC[0][0]); \
        ACC[0][1] = MFMA16(AL0, bh1, ACC[0][1]); \
        ACC[0][2] = MFMA16(AL0, bh2, ACC[0][2]); \
        ACC[0][3] = MFMA16(AL0, bh3, ACC[0][3]); \
        ACC[1][0] = MFMA16(AL1, bh0, ACC[1][0]); \
        ACC[1][1] = MFMA16(AL1, bh1, ACC[1][1]); \
        ACC[1][2] = MFMA16(AL1, bh2, ACC[1][2]); \
        ACC[1][3] = MFMA16(AL1, bh3, ACC[1][3]); \
        ACC[0][0] = MFMA16(AH0, bl0, ACC[0][0]); \
        ACC[0][1] = MFMA16(AH0, bl1, ACC[0][1]); \
        ACC[0][2] = MFMA16(AH0, bl2, ACC[0][2]); \
        ACC[0][3] = MFMA16(AH0, bl3, ACC[0][3]); \
        ACC[1][0] = MFMA16(AH1, bl0, ACC[1][0]); \
        ACC[1][1] = MFMA16(AH1, bl1, ACC[1][1]); \
        ACC[1][2] = MFMA16(AH1, bl2, ACC[1][2]); \
        ACC[1][3] = MFMA16(AH1, bl3, ACC[1][3]); }

    f32x4 acc0[2][4], acc1[2][4];
    #pragma unroll
    for (int m = 0; m < 2; ++m)
        #pragma unroll
        for (int c = 0; c < 4; ++c) {
            acc0[m][c] = (f32x4){0.f,0.f,0.f,0.f};
            acc1[m][c] = (f32x4){0.f,0.f,0.f,0.f};
        }

    // prologue: stages 0,1 -> buffers 0,1 (10 loads in flight/thread)
    STAGE(0, 0, 0);
    STAGE(0, 1, 40960);

    int cb = 0;                 // compute buffer = t % 3
    int sb = 81920;             // stage buffer for tau = t+2
    for (int t = 0; t < 31; ++t) {
        PIPE_WAIT5();           // stage t landed
        if (t <= 29) {
            const int tau = t + 2;
            STAGE(tau >> 1, tau & 1, sb);
        }
        if (!(t & 1)) { COMPUTE(acc0, cb); }
        else          { COMPUTE(acc1, cb); }
        cb += 40960; cb = (cb == 122880) ? 0 : cb;
        sb += 40960; sb = (sb == 122880) ? 0 : sb;
    }
    PIPE_WAIT0();               // last stage (31) landed
    COMPUTE(acc1, cb);
    #undef STAGE
    #undef COMPUTE
    #undef CONVA

    __syncthreads();   // compute done; all LDS reusable

    // ---- epilogue: stats + LDS-bounce coalesced hi/lo writes ----
    float st1[8], st2[8], stq[8];
    #pragma unroll
    for (int s = 0; s < 8; ++s) { st1[s] = 0.f; st2[s] = 0.f; stq[s] = 0.f; }

    f16* dump = (f16*)smem;   // 64 rows x 512 cols f16 = 64KB @ [0,65536)

    #define DUMP_HI(ACC, CQ) { \
        _Pragma("unroll") \
        for (int c = 0; c < 4; ++c) { \
            const int col = ((CQ) << 8) + (wc << 6) + (c << 4) + l15; \
            const float a1 = a[col]; \
            const float a2 = a[512 + col]; \
            _Pragma("unroll") \
            for (int m = 0; m < 2; ++m) \
            _Pragma("unroll") \
            for (int j = 0; j < 4; ++j) { \
                const float v = ACC[m][c][j]; \
                const int slot = (m << 2) + j; \
                st1[slot] = fmaf(v, a1, st1[slot]); \
                st2[slot] = fmaf(v, a2, st2[slot]); \
                stq[slot] = fmaf(v, v,  stq[slot]); \
                const int row = (wr << 5) + (m << 4) + (g << 2) + j; \
                dump[(row << 9) + col] = (f16)v; \
            } } }

    #define DUMP_LO(ACC, CQ) { \
        _Pragma("unroll") \
        for (int c = 0; c < 4; ++c) { \
            const int col = ((CQ) << 8) + (wc << 6) + (c << 4) + l15; \
            _Pragma("unroll") \
            for (int m = 0; m < 2; ++m) \
            _Pragma("unroll") \
            for (int j = 0; j < 4; ++j) { \
                const float v = ACC[m][c][j]; \
                const f16 h = (f16)v; \
                const int row = (wr << 5) + (m << 4) + (g << 2) + j; \
                dump[(row << 9) + col] = (f16)(v - (float)h); \
            } } }

    DUMP_HI(acc0, 0); DUMP_HI(acc1, 1);
    __syncthreads();
    {   // coalesced store of hi: thread covers 64 consecutive f16 (128B)
        const f16* srcp = dump + (tid << 6);
        f16* dstp = Whh + ((size_t)rowbase << 9) + (tid << 6);
        #pragma unroll
        for (int k = 0; k < 8; ++k)
            *(f16x8*)(dstp + (k << 3)) = *(const f16x8*)(srcp + (k << 3));
    }
    __syncthreads();
    DUMP_LO(acc0, 0); DUMP_LO(acc1, 1);
    __syncthreads();
    {
        const f16* srcp = dump + (tid << 6);
        f16* dstp = Whl + ((size_t)rowbase << 9) + (tid << 6);
        #pragma unroll
        for (int k = 0; k < 8; ++k)
            *(f16x8*)(dstp + (k << 3)) = *(const f16x8*)(srcp + (k << 3));
    }
    #undef DUMP_HI
    #undef DUMP_LO

    #pragma unroll
    for (int mask = 1; mask < 16; mask <<= 1)
        #pragma unroll
        for (int s = 0; s < 8; ++s) {
            st1[s] += __shfl_xor(st1[s], mask);
            st2[s] += __shfl_xor(st2[s], mask);
            stq[s] += __shfl_xor(stq[s], mask);
        }
    if (l15 == 0) {
        #pragma unroll
        for (int s = 0; s < 8; ++s) {
            const int rl = (wr << 5) + ((s >> 2) << 4) + (g << 2) + (s & 3);
            float* sp = (float*)(smem + 65536) + ((rl << 2) + wc) * 3;
            sp[0] = st1[s]; sp[1] = st2[s]; sp[2] = stq[s];
        }
    }
    __syncthreads();
    if (tid < 64) {
        float s1 = 0.f, s2 = 0.f, s3 = 0.f;
        #pragma unroll
        for (int wv = 0; wv < 4; ++wv) {
            const float* sp = (const float*)(smem + 65536) + ((tid << 2) + wv) * 3;
            s1 += sp[0]; s2 += sp[1]; s3 += sp[2];
        }
        Wh1[rowbase + tid] = s1; Wh2[rowbase + tid] = s2; sq[rowbase + tid] = s3;
    }
}

// ---------- Kernel C: single-pass f16 gram, 2-phase LDS dbuf, fused top-8 ----------
// (verbatim round-9 version — proven)
__global__ __launch_bounds__(512, 1) void k_gram_topk8(
    const f16* __restrict__ Whh, const float* __restrict__ sq,
    int* __restrict__ topk8)
{
    __shared__ __align__(16) unsigned char smem[81920];

    const int bid = blockIdx.x;
    const int swz = ((bid & 7) << 5) + (bid >> 3);
    const int p   = swz >> 4;
    const int rt  = swz & 15;
    const int rowbase  = (p << 10) + (rt << 6);
    const int colPanel = p << 10;

    const int tid  = threadIdx.x;
    const int w    = tid >> 6;
    const int wr   = w >> 2, wc = w & 3;
    const int lane = tid & 63;
    const int l15  = lane & 15;
    const int g    = lane >> 4;
    const int r8   = lane >> 3;
    const int k7   = lane & 7;
    const int sw2  = ((k7 ^ r8) << 4);
    const int q0x  = ((g ^ (lane & 7)) << 4);

    const int rowA = tid >> 3;
    const int k7A  = tid & 7;
    const int aswz = ((k7A ^ (rowA & 7)) << 4);

    const char* WB = (const char*)Whh;

    const int aoff0 = 32768 + (((wr << 5) +  0 + l15) << 7) + q0x;
    const int aoff1 = 32768 + (((wr << 5) + 16 + l15) << 7) + q0x;
    const int boff0 = (((wc << 6) +  0 + l15) << 7) + q0x;
    const int boff1 = (((wc << 6) + 16 + l15) << 7) + q0x;
    const int boff2 = (((wc << 6) + 32 + l15) << 7) + q0x;
    const int boff3 = (((wc << 6) + 48 + l15) << 7) + q0x;

    f32x4 acc[2][4];
    #pragma unroll
    for (int m = 0; m < 2; ++m)
        #pragma unroll
        for (int c = 0; c < 4; ++c) acc[m][c] = (f32x4){0.f,0.f,0.f,0.f};

    unsigned k4[8][4];
    #pragma unroll
    for (int s = 0; s < 8; ++s)
        #pragma unroll
        for (int q = 0; q < 4; ++q) k4[s][q] = 0u;

    #define STAGE_G(t) { \
        const int ct_ = (t) >> 3, kc_ = (t) & 7; \
        const int bufb_ = ((t) & 1) * 40960; \
        size_t gB_ = ((size_t)(colPanel + (ct_ << 8) + (w << 5) + r8) << 10) + (kc_ << 7) + sw2; \
        int ldsB_ = bufb_ + (w << 12) + (lane << 4); \
        _Pragma("unroll") \
        for (int j_ = 0; j_ < 4; ++j_) { \
            gl16(WB + gB_, smem + ldsB_); \
            gB_ += (size_t)8 << 10; ldsB_ += 1024; \
        } \
        size_t gA_ = ((size_t)(rowbase + rowA) << 10) + (kc_ << 7) + aswz; \
        gl16(WB + gA_, smem + bufb_ + 32768 + (tid << 4)); \
    }

    STAGE_G(0);

    for (int t = 0; t < 32; ++t) {
        __syncthreads();
        if (t < 31) STAGE_G(t + 1);
        const int bufb = (t & 1) * 40960;

        #pragma unroll
        for (int s = 0; s < 2; ++s) {
            const int sx = s << 6;
            f16x8 a0 = *(const f16x8*)(smem + bufb + (aoff0 ^ sx));
            f16x8 a1 = *(const f16x8*)(smem + bufb + (aoff1 ^ sx));
            f16x8 b0 = *(const f16x8*)(smem + bufb + (boff0 ^ sx));
            f16x8 b1 = *(const f16x8*)(smem + bufb + (boff1 ^ sx));
            f16x8 b2 = *(const f16x8*)(smem + bufb + (boff2 ^ sx));
            f16x8 b3 = *(const f16x8*)(smem + bufb + (boff3 ^ sx));
            acc[0][0] = MFMA16(a0, b0, acc[0][0]);
            acc[0][1] = MFMA16(a0, b1, acc[0][1]);
            acc[0][2] = MFMA16(a0, b2, acc[0][2]);
            acc[0][3] = MFMA16(a0, b3, acc[0][3]);
            acc[1][0] = MFMA16(a1, b0, acc[1][0]);
            acc[1][1] = MFMA16(a1, b1, acc[1][1]);
            acc[1][2] = MFMA16(a1, b2, acc[1][2]);
            acc[1][3] = MFMA16(a1, b3, acc[1][3]);
        }

        if ((t & 7) == 7) {
            const int ct = t >> 3;
            #pragma unroll
            for (int c = 0; c < 4; ++c) {
                const int cl = (ct << 8) + (wc << 6) + (c << 4) + l15;
                const float sqc = sq[colPanel + cl];
                #pragma unroll
                for (int m = 0; m < 2; ++m)
                    #pragma unroll
                    for (int j = 0; j < 4; ++j) {
                        float sc = fmaf(2.f, acc[m][c][j], -sqc);
                        unsigned key = pack_key(sc, cl);
                        INSK4(k4[(m << 2) + j], key);
                    }
                acc[0][c] = (f32x4){0.f,0.f,0.f,0.f};
                acc[1][c] = (f32x4){0.f,0.f,0.f,0.f};
            }
        }
    }

    unsigned k8[8][8];
    #pragma unroll
    for (int s = 0; s < 8; ++s) {
        #pragma unroll
        for (int q = 0; q < 4; ++q) { k8[s][q] = k4[s][q]; k8[s][4 + q] = 0u; }
    }
    #pragma unroll
    for (int msk = 1; msk < 16; msk <<= 1) {
        #pragma unroll
        for (int s = 0; s < 8; ++s) { MERGE8(k8[s], msk); }
    }

    if (l15 == 0) {
        #pragma unroll
        for (int s = 0; s < 8; ++s) {
            const int row_local = ((s >> 2) << 4) + (g << 2) + (s & 3);
            const int off = ((((wr << 5) + row_local) << 2) + wc) << 5;
            *(uint4*)(smem + off)      = make_uint4(k8[s][0], k8[s][1], k8[s][2], k8[s][3]);
            *(uint4*)(smem + off + 16) = make_uint4(k8[s][4], k8[s][5], k8[s][6], k8[s][7]);
        }
    }
    __syncthreads();
    if (tid < 64) {
        const unsigned* bp = (const unsigned*)smem + (tid << 5);
        unsigned kk[8];
        #pragma unroll
        for (int s = 0; s < 8; ++s) kk[s] = bp[s];
        #pragma unroll
        for (int wv = 1; wv < 4; ++wv)
            #pragma unroll
            for (int s = 0; s < 8; ++s) { unsigned x = bp[(wv << 3) + s]; INSK8(kk, x); }
        #pragma unroll
        for (int s = 0; s < 8; ++s)
            topk8[(((size_t)(rowbase + tid)) << 3) + s] = 1023 - (int)(kk[s] & 1023u);
    }
    #undef STAGE_G
}

// ---------- Kernel D: exact rescore (fdot2) + softmax + hi-only aggregate + elu ----------
// (unchanged from round 13)
__global__ __launch_bounds__(256) void k_rescore_agg(
    const f16* __restrict__ Whh, const f16* __restrict__ Whl,
    const float* __restrict__ Wh1, const float* __restrict__ Wh2,
    const float* __restrict__ sq, const int* __restrict__ topk8,
    float* __restrict__ out)
{
    const int bid = blockIdx.x;
    const int swz = ((bid & 7) << 9) + (bid >> 3);
    const int tid  = threadIdx.x;
    const int lane = tid & 63;
    const int r    = (swz << 2) + (tid >> 6);
    const int p    = r >> 10;
    const int i    = r & 1023;
    const int rb   = p << 10;

    const size_t ro = (size_t)r * D_ + (lane << 3);
    f16x8 ah = *(const f16x8*)(Whh + ro);
    f16x8 al = *(const f16x8*)(Whl + ro);

    int cid[8];
    {
        int4 t0 = *(const int4*)(topk8 + ((size_t)r << 3));
        int4 t1 = *(const int4*)(topk8 + ((size_t)r << 3) + 4);
        cid[0]=t0.x; cid[1]=t0.y; cid[2]=t0.z; cid[3]=t0.w;
        cid[4]=t1.x; cid[5]=t1.y; cid[6]=t1.z; cid[7]=t1.w;
    }

    float dp[8];
    #pragma unroll
    for (int c = 0; c < 8; ++c) {
        const size_t co = (size_t)(rb + cid[c]) * D_ + (lane << 3);
        f16x8 bh = *(const f16x8*)(Whh + co);
        f16x8 bl = *(const f16x8*)(Whl + co);
        float s = 0.f;
        s = fdot8(ah, bh, s);
        s = fdot8(ah, bl, s);
        s = fdot8(al, bh, s);
        dp[c] = s;
    }
    #pragma unroll
    for (int off = 32; off > 0; off >>= 1)
        #pragma unroll
        for (int c = 0; c < 8; ++c) dp[c] += __shfl_xor(dp[c], off);

    float tv[4] = {-3.4e38f,-3.4e38f,-3.4e38f,-3.4e38f};
    int   ti[4] = {0x7FFFFFFF,0x7FFFFFFF,0x7FFFFFFF,0x7FFFFFFF};
    #pragma unroll
    for (int c = 0; c < 8; ++c) {
        float sc = fmaf(2.f, dp[c], -sq[rb + cid[c]]);
        INS4T(tv, ti, sc, cid[c]);
    }

    const int  tM = i - 1, tC = i, tP = i + 1;
    const bool vM = (i > 0), vP = (i < T_ - 1);
    const int s0 = ti[0], s1 = ti[1], s2 = ti[2], s3 = ti[3];

    bool u0 = !((vM && s0 == tM) || (s0 == tC) || (vP && s0 == tP));
    bool u1 = !((vM && s1 == tM) || (s1 == tC) || (vP && s1 == tP));
    bool u2 = !((vM && s2 == tM) || (s2 == tC) || (vP && s2 == tP));
    bool u3 = !((vM && s3 == tM) || (s3 == tC) || (vP && s3 == tP));

    int  ci[7] = { vM ? tM : 0, tC, vP ? tP : 0, s0, s1, s2, s3 };
    bool cv[7] = { vM, true, vP, u0, u1, u2, u3 };

    f16x8 vhq[7];
    #pragma unroll
    for (int q = 0; q < 7; ++q)
        vhq[q] = *(const f16x8*)(Whh + (size_t)(rb + ci[q]) * D_ + (lane << 3));

    const float e1 = Wh1[r];
    float ev[7];
    float m = -3.4e38f;
    #pragma unroll
    for (int q = 0; q < 7; ++q) {
        float e = e1 + Wh2[rb + ci[q]];
        e = (e > 0.f) ? e : ALPHA_ * e;
        e = cv[q] ? e : -3.4e38f;
        ev[q] = e;
        m = fmaxf(m, e);
    }
    float wsum = 0.f;
    #pragma unroll
    for (int q = 0; q < 7; ++q) {
        float wq = cv[q] ? expf(ev[q] - m) : 0.f;
        ev[q] = wq;
        wsum += wq;
    }
    #pragma unroll
    for (int q = 0; q < 7; ++q) ev[q] /= wsum;

    float A[8] = {0.f,0.f,0.f,0.f,0.f,0.f,0.f,0.f};
    #pragma unroll
    for (int q = 0; q < 7; ++q) {
        const float wq = ev[q];
        #pragma unroll
        for (int e = 0; e < 8; ++e) A[e] = fmaf(wq, (float)vhq[q][e], A[e]);
    }
    #pragma unroll
    for (int e = 0; e < 8; ++e)
        A[e] = (A[e] > 0.f) ? A[e] : expm1f(A[e]);

    const int blk = p & 1, b = p >> 1;
    float* dst = out + (size_t)blk * ((size_t)BS_ * T_ * D_)
               + ((size_t)((b << 10) + i)) * D_ + (lane << 3);
    *(float4*)(dst)     = make_float4(A[0], A[1], A[2], A[3]);
    *(float4*)(dst + 4) = make_float4(A[4], A[5], A[6], A[7]);
}

extern "C" void kernel_launch(void* const* d_in, const int* in_sizes, int n_in,
                              void* d_out, int out_size, void* d_ws, size_t ws_size,
                              hipStream_t stream)
{
    const float* xa = (const float*)d_in[0];
    const float* xv = (const float*)d_in[1];
    const float* W  = (const float*)d_in[2];
    const float* a  = (const float*)d_in[3];
    float* out = (float*)d_out;

    f16* Whh    = (f16*)d_ws;                          // 16.8 MB
    f16* Whl    = Whh + (size_t)NROWS_ * D_;           // 16.8 MB
    f16* WTh    = Whl + (size_t)NROWS_ * D_;           // 0.5 MB
    f16* WTl    = WTh + (size_t)D_ * D_;               // 0.5 MB
    float* Wh1  = (float*)(WTl + (size_t)D_ * D_);
    float* Wh2  = Wh1 + NROWS_;
    float* sq   = Wh2 + NROWS_;
    int* topk8  = (int*)(sq + NROWS_);                 // 0.5 MB

    k_splitW     <<<dim3(64),   dim3(256), 0, stream>>>(W, WTh, WTl);
    k_gemm_wh    <<<dim3(256),  dim3(512), 0, stream>>>(xa, xv, WTh, WTl, a, Whh, Whl, Wh1, Wh2, sq);
    k_gram_topk8 <<<dim3(256),  dim3(512), 0, stream>>>(Whh, sq, topk8);
    k_rescore_agg<<<dim3(4096), dim3(256), 0, stream>>>(Whh, Whl, Wh1, Wh2, sq, topk8, out);
}

// Round 16
// 117.168 us; speedup vs baseline: 1.1783x; 1.0371x over previous
//
#include <hip/hip_runtime.h>
#include <math.h>

#define T_ 1024
#define BS_ 8
#define D_ 512
#define NROWS_ (BS_*2*T_)   // 16384
#define ALPHA_ 0.1f

typedef _Float16 f16;
typedef _Float16 f16x8 __attribute__((ext_vector_type(8)));
typedef _Float16 f16x4 __attribute__((ext_vector_type(4)));
typedef _Float16 f16x2 __attribute__((ext_vector_type(2)));
typedef float f32x4 __attribute__((ext_vector_type(4)));

#define MFMA16(A,B,C) __builtin_amdgcn_mfma_f32_16x16x32_f16((A),(B),(C),0,0,0)

__device__ __forceinline__ void gl16(const void* g, void* l) {
    __builtin_amdgcn_global_load_lds(
        (const __attribute__((address_space(1))) unsigned int*)g,
        (__attribute__((address_space(3))) unsigned int*)l, 16, 0, 0);
}

#if __has_builtin(__builtin_amdgcn_fdot2)
__device__ __forceinline__ float fdot2p(f16x2 a, f16x2 b, float c) {
    return __builtin_amdgcn_fdot2(a, b, c, false);
}
#else
__device__ __forceinline__ float fdot2p(f16x2 a, f16x2 b, float c) {
    return fmaf((float)a[1], (float)b[1], fmaf((float)a[0], (float)b[0], c));
}
#endif

__device__ __forceinline__ float fdot8(const f16x8 a, const f16x8 b, float s) {
    #pragma unroll
    for (int q = 0; q < 4; ++q) {
        f16x2 aa, bb;
        aa[0] = a[2*q]; aa[1] = a[2*q+1];
        bb[0] = b[2*q]; bb[1] = b[2*q+1];
        s = fdot2p(aa, bb, s);
    }
    return s;
}

// float -> order-preserving unsigned
__device__ __forceinline__ unsigned sortable(float f) {
    unsigned u = __float_as_uint(f);
    return u ^ ((u & 0x80000000u) ? 0xFFFFFFFFu : 0x80000000u);
}
__device__ __forceinline__ unsigned pack_key(float s, int col) {
    return (sortable(s) & 0xFFFFFC00u) | (unsigned)(1023 - col);
}

#define INSK4(K, X) { \
    bool g3 = (X) > K[3], g2 = (X) > K[2], g1 = (X) > K[1], g0 = (X) > K[0]; \
    K[3] = g2 ? K[2] : (g3 ? (X) : K[3]); \
    K[2] = g1 ? K[1] : (g2 ? (X) : K[2]); \
    K[1] = g0 ? K[0] : (g1 ? (X) : K[1]); \
    K[0] = g0 ? (X) : K[0]; }

#define INSK8(K, X) { \
    bool h7=(X)>K[7],h6=(X)>K[6],h5=(X)>K[5],h4=(X)>K[4]; \
    bool h3=(X)>K[3],h2=(X)>K[2],h1=(X)>K[1],h0=(X)>K[0]; \
    K[7]=h6?K[6]:(h7?(X):K[7]); K[6]=h5?K[5]:(h6?(X):K[6]); \
    K[5]=h4?K[4]:(h5?(X):K[5]); K[4]=h3?K[3]:(h4?(X):K[4]); \
    K[3]=h2?K[2]:(h3?(X):K[3]); K[2]=h1?K[1]:(h2?(X):K[2]); \
    K[1]=h0?K[0]:(h1?(X):K[1]); K[0]=h0?(X):K[0]; }

#define CEU(a,b) { unsigned mx_ = (a) > (b) ? (a) : (b); \
    unsigned mn_ = (a) > (b) ? (b) : (a); (a) = mx_; (b) = mn_; }

#define MERGE8(K, MSK) { \
    unsigned b0=__shfl_xor(K[0],MSK), b1=__shfl_xor(K[1],MSK), \
             b2=__shfl_xor(K[2],MSK), b3=__shfl_xor(K[3],MSK), \
             b4=__shfl_xor(K[4],MSK), b5=__shfl_xor(K[5],MSK), \
             b6=__shfl_xor(K[6],MSK), b7=__shfl_xor(K[7],MSK); \
    K[0]=K[0]>b7?K[0]:b7; K[1]=K[1]>b6?K[1]:b6; \
    K[2]=K[2]>b5?K[2]:b5; K[3]=K[3]>b4?K[3]:b4; \
    K[4]=K[4]>b3?K[4]:b3; K[5]=K[5]>b2?K[5]:b2; \
    K[6]=K[6]>b1?K[6]:b1; K[7]=K[7]>b0?K[7]:b0; \
    CEU(K[0],K[4]); CEU(K[1],K[5]); CEU(K[2],K[6]); CEU(K[3],K[7]); \
    CEU(K[0],K[2]); CEU(K[1],K[3]); CEU(K[4],K[6]); CEU(K[5],K[7]); \
    CEU(K[0],K[1]); CEU(K[2],K[3]); CEU(K[4],K[5]); CEU(K[6],K[7]); }

#define BETTER(x,xi,v,vi) ((x) > (v) || ((x) == (v) && (xi) < (vi)))
#define INS4T(TV,TI,X,ID) { \
    bool g3 = BETTER(X,ID,TV[3],TI[3]), g2 = BETTER(X,ID,TV[2],TI[2]); \
    bool g1 = BETTER(X,ID,TV[1],TI[1]), g0 = BETTER(X,ID,TV[0],TI[0]); \
    TV[3] = g2 ? TV[2] : (g3 ? (X) : TV[3]); TI[3] = g2 ? TI[2] : (g3 ? (ID) : TI[3]); \
    TV[2] = g1 ? TV[1] : (g2 ? (X) : TV[2]); TI[2] = g1 ? TI[1] : (g2 ? (ID) : TI[2]); \
    TV[1] = g0 ? TV[0] : (g1 ? (X) : TV[1]); TI[1] = g0 ? TI[0] : (g1 ? (ID) : TI[1]); \
    TV[0] = g0 ? (X) : TV[0]; TI[0] = g0 ? (ID) : TI[0]; }

// ---------- Kernel 0: W (FIN x FOUT) -> WT[n][k] f16 hi/lo ----------
__global__ __launch_bounds__(256) void k_splitW(
    const float* __restrict__ W, f16* __restrict__ WTh, f16* __restrict__ WTl)
{
    __shared__ float tile[64][65];
    const int tid = threadIdx.x;
    const int tk = (blockIdx.x >> 3) << 6, tn = (blockIdx.x & 7) << 6;
    const int r0 = tid >> 4, c4 = (tid & 15) << 2;

    #pragma unroll
    for (int rr = 0; rr < 4; ++rr) {
        int k = r0 + (rr << 4);
        float4 v = *(const float4*)(W + (size_t)(tk + k) * D_ + tn + c4);
        tile[k][c4+0] = v.x; tile[k][c4+1] = v.y;
        tile[k][c4+2] = v.z; tile[k][c4+3] = v.w;
    }
    __syncthreads();
    #pragma unroll
    for (int rr = 0; rr < 4; ++rr) {
        int n = r0 + (rr << 4);
        f16x4 h, l;
        #pragma unroll
        for (int i = 0; i < 4; ++i) {
            float x = tile[c4 + i][n];
            f16 hh = (f16)x; h[i] = hh; l[i] = (f16)(x - (float)hh);
        }
        *(f16x4*)(WTh + (size_t)(tn + n) * D_ + tk + c4) = h;
        *(f16x4*)(WTl + (size_t)(tn + n) * D_ + tk + c4) = l;
    }
}

// ---------- Kernel A: Wh = h @ W (split-fp16 MFMA, 2-phase dbuf, A-in-reg) ----------
// r6 design — best measured gemm (46.5µs, round-7 bench). Verbatim.
// grid = 256 blocks x 512 threads (8 waves: wr 2 x wc 4); block = 64 rows x 512 cols
// 16 steps: kc(8, K=64 each) outer x ct(2, 256 cols each) inner; buf = step&1
// LDS: dbuf 2 x (Bh 32KB + Bl 32KB) = 128KB @0; sa 4KB @131072; stats reuse @0
__global__ __launch_bounds__(512, 2) void k_gemm_wh(
    const float* __restrict__ xa, const float* __restrict__ xv,
    const f16* __restrict__ WTh, const f16* __restrict__ WTl,
    const float* __restrict__ a,
    f16* __restrict__ Whh, f16* __restrict__ Whl,
    float* __restrict__ Wh1, float* __restrict__ Wh2, float* __restrict__ sq)
{
    __shared__ __align__(16) unsigned char smem[135168];

    const int tid  = threadIdx.x;
    const int w    = tid >> 6;
    const int wr   = w >> 2, wc = w & 3;
    const int lane = tid & 63;
    const int l15  = lane & 15;
    const int g    = lane >> 4;
    const int r8   = lane >> 3;
    const int k7   = lane & 7;
    const int sw2  = ((k7 ^ r8) << 4);
    const int q0x  = ((g ^ (lane & 7)) << 4);
    const int rowbase = blockIdx.x << 6;

    if (tid < 256)
        *(float4*)(smem + 131072 + (tid << 4)) = *(const float4*)(a + (tid << 2));

    const int qp = rowbase >> 10;
    const float* xsrc = ((qp & 1) ? xv : xa)
                      + (size_t)((qp >> 1) * 1024 + (rowbase & 1023)) * D_;
    const int arow = (wr << 5) + l15;

    const char* WThB = (const char*)WTh;
    const char* WTlB = (const char*)WTl;

    const int bo0 = (((wc << 6) +  0 + l15) << 7) + q0x;
    const int bo1 = (((wc << 6) + 16 + l15) << 7) + q0x;
    const int bo2 = (((wc << 6) + 32 + l15) << 7) + q0x;
    const int bo3 = (((wc << 6) + 48 + l15) << 7) + q0x;

    #define STAGE_B(ct_, kc_, buf_) { \
        size_t gB_ = ((size_t)(((ct_) << 8) + (w << 5) + r8) << 10) + ((kc_) << 7) + sw2; \
        int ldsB_ = (buf_) * 65536 + (w << 12) + (lane << 4); \
        _Pragma("unroll") \
        for (int j_ = 0; j_ < 4; ++j_) { \
            gl16(WThB + gB_, smem + ldsB_); \
            gl16(WTlB + gB_, smem + 32768 + ldsB_); \
            gB_ += (size_t)8 << 10; ldsB_ += 1024; } }

    // A fragment loads: lane -> rows {arow, arow+16}, k window s: kc*64+s*32+g*8..+7
    #define LOAD_A(dst_, kc_) { \
        _Pragma("unroll") \
        for (int r_ = 0; r_ < 2; ++r_) { \
            const float* p_ = xsrc + (size_t)(arow + (r_ << 4)) * D_ + ((kc_) << 6) + (g << 3); \
            dst_[(r_ << 2) + 0] = *(const float4*)(p_); \
            dst_[(r_ << 2) + 1] = *(const float4*)(p_ + 4); \
            dst_[(r_ << 2) + 2] = *(const float4*)(p_ + 32); \
            dst_[(r_ << 2) + 3] = *(const float4*)(p_ + 36); } }

    #define CONV_A(src_) { \
        _Pragma("unroll") \
        for (int r_ = 0; r_ < 2; ++r_) \
        _Pragma("unroll") \
        for (int s_ = 0; s_ < 2; ++s_) { \
            float4 v0_ = src_[(r_ << 2) + (s_ << 1)]; \
            float4 v1_ = src_[(r_ << 2) + (s_ << 1) + 1]; \
            float xs_[8] = {v0_.x,v0_.y,v0_.z,v0_.w,v1_.x,v1_.y,v1_.z,v1_.w}; \
            f16x8 h_, l_; \
            _Pragma("unroll") \
            for (int e_ = 0; e_ < 8; ++e_) { \
                f16 hh_ = (f16)xs_[e_]; h_[e_] = hh_; l_[e_] = (f16)(xs_[e_] - (float)hh_); } \
            AH[r_][s_] = h_; AL[r_][s_] = l_; } }

    f32x4 acc[2][2][4];
    #pragma unroll
    for (int ct = 0; ct < 2; ++ct)
        #pragma unroll
        for (int m = 0; m < 2; ++m)
            #pragma unroll
            for (int c = 0; c < 4; ++c) acc[ct][m][c] = (f32x4){0.f,0.f,0.f,0.f};

    float4 aR[8];
    f16x8 AH[2][2], AL[2][2];

    LOAD_A(aR, 0);
    STAGE_B(0, 0, 0);

    #pragma unroll
    for (int t = 0; t < 16; ++t) {
        const int kc = t >> 1, ct = t & 1, bufb = (t & 1) * 65536;
        __syncthreads();
        if (t < 15) STAGE_B((t + 1) & 1, (t + 1) >> 1, (t + 1) & 1);
        if (ct == 0) { CONV_A(aR); }
        else if (kc < 7) { LOAD_A(aR, kc + 1); }   // prefetch next kc (1-step cover)

        #pragma unroll
        for (int s = 0; s < 2; ++s) {
            const int sx = s << 6;
            f16x8 bh0 = *(const f16x8*)(smem + bufb + (bo0 ^ sx));
            f16x8 bh1 = *(const f16x8*)(smem + bufb + (bo1 ^ sx));
            f16x8 bh2 = *(const f16x8*)(smem + bufb + (bo2 ^ sx));
            f16x8 bh3 = *(const f16x8*)(smem + bufb + (bo3 ^ sx));
            f16x8 bl0 = *(const f16x8*)(smem + bufb + 32768 + (bo0 ^ sx));
            f16x8 bl1 = *(const f16x8*)(smem + bufb + 32768 + (bo1 ^ sx));
            f16x8 bl2 = *(const f16x8*)(smem + bufb + 32768 + (bo2 ^ sx));
            f16x8 bl3 = *(const f16x8*)(smem + bufb + 32768 + (bo3 ^ sx));

            acc[ct][0][0] = MFMA16(AH[0][s], bh0, acc[ct][0][0]);
            acc[ct][0][1] = MFMA16(AH[0][s], bh1, acc[ct][0][1]);
            acc[ct][0][2] = MFMA16(AH[0][s], bh2, acc[ct][0][2]);
            acc[ct][0][3] = MFMA16(AH[0][s], bh3, acc[ct][0][3]);
            acc[ct][1][0] = MFMA16(AH[1][s], bh0, acc[ct][1][0]);
            acc[ct][1][1] = MFMA16(AH[1][s], bh1, acc[ct][1][1]);
            acc[ct][1][2] = MFMA16(AH[1][s], bh2, acc[ct][1][2]);
            acc[ct][1][3] = MFMA16(AH[1][s], bh3, acc[ct][1][3]);
            acc[ct][0][0] = MFMA16(AL[0][s], bh0, acc[ct][0][0]);
            acc[ct][0][1] = MFMA16(AL[0][s], bh1, acc[ct][0][1]);
            acc[ct][0][2] = MFMA16(AL[0][s], bh2, acc[ct][0][2]);
            acc[ct][0][3] = MFMA16(AL[0][s], bh3, acc[ct][0][3]);
            acc[ct][1][0] = MFMA16(AL[1][s], bh0, acc[ct][1][0]);
            acc[ct][1][1] = MFMA16(AL[1][s], bh1, acc[ct][1][1]);
            acc[ct][1][2] = MFMA16(AL[1][s], bh2, acc[ct][1][2]);
            acc[ct][1][3] = MFMA16(AL[1][s], bh3, acc[ct][1][3]);
            acc[ct][0][0] = MFMA16(AH[0][s], bl0, acc[ct][0][0]);
            acc[ct][0][1] = MFMA16(AH[0][s], bl1, acc[ct][0][1]);
            acc[ct][0][2] = MFMA16(AH[0][s], bl2, acc[ct][0][2]);
            acc[ct][0][3] = MFMA16(AH[0][s], bl3, acc[ct][0][3]);
            acc[ct][1][0] = MFMA16(AH[1][s], bl0, acc[ct][1][0]);
            acc[ct][1][1] = MFMA16(AH[1][s], bl1, acc[ct][1][1]);
            acc[ct][1][2] = MFMA16(AH[1][s], bl2, acc[ct][1][2]);
            acc[ct][1][3] = MFMA16(AH[1][s], bl3, acc[ct][1][3]);
        }
    }
    #undef STAGE_B
    #undef LOAD_A
    #undef CONV_A

    __syncthreads();   // all compute done; smem[0,3KB) reusable for stats

    float st1[8], st2[8], stq[8];
    #pragma unroll
    for (int s = 0; s < 8; ++s) { st1[s] = 0.f; st2[s] = 0.f; stq[s] = 0.f; }

    #pragma unroll
    for (int ct = 0; ct < 2; ++ct)
        #pragma unroll
        for (int c = 0; c < 4; ++c) {
            const int col = (ct << 8) + (wc << 6) + (c << 4) + l15;
            const float a1 = *(const float*)(smem + 131072 + (col << 2));
            const float a2 = *(const float*)(smem + 131072 + 2048 + (col << 2));
            #pragma unroll
            for (int m = 0; m < 2; ++m)
                #pragma unroll
                for (int j = 0; j < 4; ++j) {
                    const float v = acc[ct][m][c][j];
                    const int slot = (m << 2) + j;
                    st1[slot] = fmaf(v, a1, st1[slot]);
                    st2[slot] = fmaf(v, a2, st2[slot]);
                    stq[slot] = fmaf(v, v,  stq[slot]);
                    f16 h = (f16)v; f16 l = (f16)(v - (float)h);
                    const size_t off = (size_t)(rowbase + (wr << 5) + (m << 4) + (g << 2) + j) * D_ + col;
                    Whh[off] = h; Whl[off] = l;
                }
        }

    #pragma unroll
    for (int mask = 1; mask < 16; mask <<= 1)
        #pragma unroll
        for (int s = 0; s < 8; ++s) {
            st1[s] += __shfl_xor(st1[s], mask);
            st2[s] += __shfl_xor(st2[s], mask);
            stq[s] += __shfl_xor(stq[s], mask);
        }
    if (l15 == 0) {
        #pragma unroll
        for (int s = 0; s < 8; ++s) {
            const int rl = (wr << 5) + ((s >> 2) << 4) + (g << 2) + (s & 3);
            float* sp = (float*)smem + ((rl << 2) + wc) * 3;
            sp[0] = st1[s]; sp[1] = st2[s]; sp[2] = stq[s];
        }
    }
    __syncthreads();
    if (tid < 64) {
        float s1 = 0.f, s2 = 0.f, s3 = 0.f;
        #pragma unroll
        for (int wv = 0; wv < 4; ++wv) {
            const float* sp = (const float*)smem + ((tid << 2) + wv) * 3;
            s1 += sp[0]; s2 += sp[1]; s3 += sp[2];
        }
        Wh1[rowbase + tid] = s1; Wh2[rowbase + tid] = s2; sq[rowbase + tid] = s3;
    }
}

// ---------- Kernel C: single-pass f16 gram, 2-phase LDS dbuf, fused top-8 ----------
// (verbatim round-9 version — proven)
__global__ __launch_bounds__(512, 1) void k_gram_topk8(
    const f16* __restrict__ Whh, const float* __restrict__ sq,
    int* __restrict__ topk8)
{
    __shared__ __align__(16) unsigned char smem[81920];

    const int bid = blockIdx.x;
    const int swz = ((bid & 7) << 5) + (bid >> 3);
    const int p   = swz >> 4;
    const int rt  = swz & 15;
    const int rowbase  = (p << 10) + (rt << 6);
    const int colPanel = p << 10;

    const int tid  = threadIdx.x;
    const int w    = tid >> 6;
    const int wr   = w >> 2, wc = w & 3;
    const int lane = tid & 63;
    const int l15  = lane & 15;
    const int g    = lane >> 4;
    const int r8   = lane >> 3;
    const int k7   = lane & 7;
    const int sw2  = ((k7 ^ r8) << 4);
    const int q0x  = ((g ^ (lane & 7)) << 4);

    const int rowA = tid >> 3;
    const int k7A  = tid & 7;
    const int aswz = ((k7A ^ (rowA & 7)) << 4);

    const char* WB = (const char*)Whh;

    const int aoff0 = 32768 + (((wr << 5) +  0 + l15) << 7) + q0x;
    const int aoff1 = 32768 + (((wr << 5) + 16 + l15) << 7) + q0x;
    const int boff0 = (((wc << 6) +  0 + l15) << 7) + q0x;
    const int boff1 = (((wc << 6) + 16 + l15) << 7) + q0x;
    const int boff2 = (((wc << 6) + 32 + l15) << 7) + q0x;
    const int boff3 = (((wc << 6) + 48 + l15) << 7) + q0x;

    f32x4 acc[2][4];
    #pragma unroll
    for (int m = 0; m < 2; ++m)
        #pragma unroll
        for (int c = 0; c < 4; ++c) acc[m][c] = (f32x4){0.f,0.f,0.f,0.f};

    unsigned k4[8][4];
    #pragma unroll
    for (int s = 0; s < 8; ++s)
        #pragma unroll
        for (int q = 0; q < 4; ++q) k4[s][q] = 0u;

    #define STAGE_G(t) { \
        const int ct_ = (t) >> 3, kc_ = (t) & 7; \
        const int bufb_ = ((t) & 1) * 40960; \
        size_t gB_ = ((size_t)(colPanel + (ct_ << 8) + (w << 5) + r8) << 10) + (kc_ << 7) + sw2; \
        int ldsB_ = bufb_ + (w << 12) + (lane << 4); \
        _Pragma("unroll") \
        for (int j_ = 0; j_ < 4; ++j_) { \
            gl16(WB + gB_, smem + ldsB_); \
            gB_ += (size_t)8 << 10; ldsB_ += 1024; \
        } \
        size_t gA_ = ((size_t)(rowbase + rowA) << 10) + (kc_ << 7) + aswz; \
        gl16(WB + gA_, smem + bufb_ + 32768 + (tid << 4)); \
    }

    STAGE_G(0);

    for (int t = 0; t < 32; ++t) {
        __syncthreads();
        if (t < 31) STAGE_G(t + 1);
        const int bufb = (t & 1) * 40960;

        #pragma unroll
        for (int s = 0; s < 2; ++s) {
            const int sx = s << 6;
            f16x8 a0 = *(const f16x8*)(smem + bufb + (aoff0 ^ sx));
            f16x8 a1 = *(const f16x8*)(smem + bufb + (aoff1 ^ sx));
            f16x8 b0 = *(const f16x8*)(smem + bufb + (boff0 ^ sx));
            f16x8 b1 = *(const f16x8*)(smem + bufb + (boff1 ^ sx));
            f16x8 b2 = *(const f16x8*)(smem + bufb + (boff2 ^ sx));
            f16x8 b3 = *(const f16x8*)(smem + bufb + (boff3 ^ sx));
            acc[0][0] = MFMA16(a0, b0, acc[0][0]);
            acc[0][1] = MFMA16(a0, b1, acc[0][1]);
            acc[0][2] = MFMA16(a0, b2, acc[0][2]);
            acc[0][3] = MFMA16(a0, b3, acc[0][3]);
            acc[1][0] = MFMA16(a1, b0, acc[1][0]);
            acc[1][1] = MFMA16(a1, b1, acc[1][1]);
            acc[1][2] = MFMA16(a1, b2, acc[1][2]);
            acc[1][3] = MFMA16(a1, b3, acc[1][3]);
        }

        if ((t & 7) == 7) {
            const int ct = t >> 3;
            #pragma unroll
            for (int c = 0; c < 4; ++c) {
                const int cl = (ct << 8) + (wc << 6) + (c << 4) + l15;
                const float sqc = sq[colPanel + cl];
                #pragma unroll
                for (int m = 0; m < 2; ++m)
                    #pragma unroll
                    for (int j = 0; j < 4; ++j) {
                        float sc = fmaf(2.f, acc[m][c][j], -sqc);
                        unsigned key = pack_key(sc, cl);
                        INSK4(k4[(m << 2) + j], key);
                    }
                acc[0][c] = (f32x4){0.f,0.f,0.f,0.f};
                acc[1][c] = (f32x4){0.f,0.f,0.f,0.f};
            }
        }
    }

    unsigned k8[8][8];
    #pragma unroll
    for (int s = 0; s < 8; ++s) {
        #pragma unroll
        for (int q = 0; q < 4; ++q) { k8[s][q] = k4[s][q]; k8[s][4 + q] = 0u; }
    }
    #pragma unroll
    for (int msk = 1; msk < 16; msk <<= 1) {
        #pragma unroll
        for (int s = 0; s < 8; ++s) { MERGE8(k8[s], msk); }
    }

    if (l15 == 0) {
        #pragma unroll
        for (int s = 0; s < 8; ++s) {
            const int row_local = ((s >> 2) << 4) + (g << 2) + (s & 3);
            const int off = ((((wr << 5) + row_local) << 2) + wc) << 5;
            *(uint4*)(smem + off)      = make_uint4(k8[s][0], k8[s][1], k8[s][2], k8[s][3]);
            *(uint4*)(smem + off + 16) = make_uint4(k8[s][4], k8[s][5], k8[s][6], k8[s][7]);
        }
    }
    __syncthreads();
    if (tid < 64) {
        const unsigned* bp = (const unsigned*)smem + (tid << 5);
        unsigned kk[8];
        #pragma unroll
        for (int s = 0; s < 8; ++s) kk[s] = bp[s];
        #pragma unroll
        for (int wv = 1; wv < 4; ++wv)
            #pragma unroll
            for (int s = 0; s < 8; ++s) { unsigned x = bp[(wv << 3) + s]; INSK8(kk, x); }
        #pragma unroll
        for (int s = 0; s < 8; ++s)
            topk8[(((size_t)(rowbase + tid)) << 3) + s] = 1023 - (int)(kk[s] & 1023u);
    }
    #undef STAGE_G
}

// ---------- Kernel D: exact rescore (fdot2) + softmax + hi-only aggregate + elu ----------
// (unchanged from round 13/15)
__global__ __launch_bounds__(256) void k_rescore_agg(
    const f16* __restrict__ Whh, const f16* __restrict__ Whl,
    const float* __restrict__ Wh1, const float* __restrict__ Wh2,
    const float* __restrict__ sq, const int* __restrict__ topk8,
    float* __restrict__ out)
{
    const int bid = blockIdx.x;
    const int swz = ((bid & 7) << 9) + (bid >> 3);
    const int tid  = threadIdx.x;
    const int lane = tid & 63;
    const int r    = (swz << 2) + (tid >> 6);
    const int p    = r >> 10;
    const int i    = r & 1023;
    const int rb   = p << 10;

    const size_t ro = (size_t)r * D_ + (lane << 3);
    f16x8 ah = *(const f16x8*)(Whh + ro);
    f16x8 al = *(const f16x8*)(Whl + ro);

    int cid[8];
    {
        int4 t0 = *(const int4*)(topk8 + ((size_t)r << 3));
        int4 t1 = *(const int4*)(topk8 + ((size_t)r << 3) + 4);
        cid[0]=t0.x; cid[1]=t0.y; cid[2]=t0.z; cid[3]=t0.w;
        cid[4]=t1.x; cid[5]=t1.y; cid[6]=t1.z; cid[7]=t1.w;
    }

    float dp[8];
    #pragma unroll
    for (int c = 0; c < 8; ++c) {
        const size_t co = (size_t)(rb + cid[c]) * D_ + (lane << 3);
        f16x8 bh = *(const f16x8*)(Whh + co);
        f16x8 bl = *(const f16x8*)(Whl + co);
        float s = 0.f;
        s = fdot8(ah, bh, s);
        s = fdot8(ah, bl, s);
        s = fdot8(al, bh, s);
        dp[c] = s;
    }
    #pragma unroll
    for (int off = 32; off > 0; off >>= 1)
        #pragma unroll
        for (int c = 0; c < 8; ++c) dp[c] += __shfl_xor(dp[c], off);

    float tv[4] = {-3.4e38f,-3.4e38f,-3.4e38f,-3.4e38f};
    int   ti[4] = {0x7FFFFFFF,0x7FFFFFFF,0x7FFFFFFF,0x7FFFFFFF};
    #pragma unroll
    for (int c = 0; c < 8; ++c) {
        float sc = fmaf(2.f, dp[c], -sq[rb + cid[c]]);
        INS4T(tv, ti, sc, cid[c]);
    }

    const int  tM = i - 1, tC = i, tP = i + 1;
    const bool vM = (i > 0), vP = (i < T_ - 1);
    const int s0 = ti[0], s1 = ti[1], s2 = ti[2], s3 = ti[3];

    bool u0 = !((vM && s0 == tM) || (s0 == tC) || (vP && s0 == tP));
    bool u1 = !((vM && s1 == tM) || (s1 == tC) || (vP && s1 == tP));
    bool u2 = !((vM && s2 == tM) || (s2 == tC) || (vP && s2 == tP));
    bool u3 = !((vM && s3 == tM) || (s3 == tC) || (vP && s3 == tP));

    int  ci[7] = { vM ? tM : 0, tC, vP ? tP : 0, s0, s1, s2, s3 };
    bool cv[7] = { vM, true, vP, u0, u1, u2, u3 };

    f16x8 vhq[7];
    #pragma unroll
    for (int q = 0; q < 7; ++q)
        vhq[q] = *(const f16x8*)(Whh + (size_t)(rb + ci[q]) * D_ + (lane << 3));

    const float e1 = Wh1[r];
    float ev[7];
    float m = -3.4e38f;
    #pragma unroll
    for (int q = 0; q < 7; ++q) {
        float e = e1 + Wh2[rb + ci[q]];
        e = (e > 0.f) ? e : ALPHA_ * e;
        e = cv[q] ? e : -3.4e38f;
        ev[q] = e;
        m = fmaxf(m, e);
    }
    float wsum = 0.f;
    #pragma unroll
    for (int q = 0; q < 7; ++q) {
        float wq = cv[q] ? expf(ev[q] - m) : 0.f;
        ev[q] = wq;
        wsum += wq;
    }
    #pragma unroll
    for (int q = 0; q < 7; ++q) ev[q] /= wsum;

    float A[8] = {0.f,0.f,0.f,0.f,0.f,0.f,0.f,0.f};
    #pragma unroll
    for (int q = 0; q < 7; ++q) {
        const float wq = ev[q];
        #pragma unroll
        for (int e = 0; e < 8; ++e) A[e] = fmaf(wq, (float)vhq[q][e], A[e]);
    }
    #pragma unroll
    for (int e = 0; e < 8; ++e)
        A[e] = (A[e] > 0.f) ? A[e] : expm1f(A[e]);

    const int blk = p & 1, b = p >> 1;
    float* dst = out + (size_t)blk * ((size_t)BS_ * T_ * D_)
               + ((size_t)((b << 10) + i)) * D_ + (lane << 3);
    *(float4*)(dst)     = make_float4(A[0], A[1], A[2], A[3]);
    *(float4*)(dst + 4) = make_float4(A[4], A[5], A[6], A[7]);
}

extern "C" void kernel_launch(void* const* d_in, const int* in_sizes, int n_in,
                              void* d_out, int out_size, void* d_ws, size_t ws_size,
                              hipStream_t stream)
{
    const float* xa = (const float*)d_in[0];
    const float* xv = (const float*)d_in[1];
    const float* W  = (const float*)d_in[2];
    const float* a  = (const float*)d_in[3];
    float* out = (float*)d_out;

    f16* Whh    = (f16*)d_ws;                          // 16.8 MB
    f16* Whl    = Whh + (size_t)NROWS_ * D_;           // 16.8 MB
    f16* WTh    = Whl + (size_t)NROWS_ * D_;           // 0.5 MB
    f16* WTl    = WTh + (size_t)D_ * D_;               // 0.5 MB
    float* Wh1  = (float*)(WTl + (size_t)D_ * D_);
    float* Wh2  = Wh1 + NROWS_;
    float* sq   = Wh2 + NROWS_;
    int* topk8  = (int*)(sq + NROWS_);                 // 0.5 MB

    k_splitW     <<<dim3(64),   dim3(256), 0, stream>>>(W, WTh, WTl);
    k_gemm_wh    <<<dim3(256),  dim3(512), 0, stream>>>(xa, xv, WTh, WTl, a, Whh, Whl, Wh1, Wh2, sq);
    k_gram_topk8 <<<dim3(256),  dim3(512), 0, stream>>>(Whh, sq, topk8);
    k_rescore_agg<<<dim3(4096), dim3(256), 0, stream>>>(Whh, Whl, Wh1, Wh2, sq, topk8, out);
}